// Round 5
// baseline (229.348 us; speedup 1.0000x reference)
//
#include <hip/hip_runtime.h>

typedef unsigned short u16;
typedef unsigned int u32;
typedef __bf16 bf16x8 __attribute__((ext_vector_type(8)));
typedef float f32x4 __attribute__((ext_vector_type(4)));
typedef short s16x4 __attribute__((ext_vector_type(4)));

#define AS1 __attribute__((address_space(1)))
#define AS3 __attribute__((address_space(3)))

__device__ __forceinline__ f32x4 mfma16(bf16x8 a, bf16x8 b, f32x4 c) {
    return __builtin_amdgcn_mfma_f32_16x16x32_bf16(a, b, c, 0, 0, 0);
}
// K=16 shape: B-operand layout == C/D layout (transpose-free PV)
__device__ __forceinline__ f32x4 mfma16k16(s16x4 a, s16x4 b, f32x4 c) {
    return __builtin_amdgcn_mfma_f32_16x16x16bf16_1k(a, b, c, 0, 0, 0);
}

__device__ __forceinline__ u16 f2bf(float f) {
    return __builtin_bit_cast(u16, (__bf16)f);
}

__device__ __forceinline__ void gld16(const u16* g, u16* l) {
    __builtin_amdgcn_global_load_lds((AS1 void*)g, (AS3 void*)l, 16, 0, 0);
}

// ---------------- fused fp32 -> bf16 conversion ----------------
__global__ __launch_bounds__(256) void cvt_all(const float* __restrict__ q, const float* __restrict__ k,
                                               const float* __restrict__ v, const float* __restrict__ wq,
                                               const float* __restrict__ wk, const float* __restrict__ wv,
                                               const float* __restrict__ wo, u16* __restrict__ qo,
                                               u16* __restrict__ ko, u16* __restrict__ vo,
                                               u16* __restrict__ wqo, u16* __restrict__ wko,
                                               u16* __restrict__ wvo, u16* __restrict__ woo) {
    const int y = blockIdx.y;
    const float* x; u16* o; int n;
    switch (y) {
        case 0: x = q; o = qo; n = 4 << 20; break;
        case 1: x = k; o = ko; n = 4 << 20; break;
        case 2: x = v; o = vo; n = 4 << 20; break;
        case 3: x = wq; o = wqo; n = 1 << 20; break;
        case 4: x = wk; o = wko; n = 1 << 20; break;
        case 5: x = wv; o = wvo; n = 1 << 20; break;
        default: x = wo; o = woo; n = 1 << 20; break;
    }
    int i = (blockIdx.x * 256 + threadIdx.x) * 4;
    if (i >= n) return;
    float4 vv = *(const float4*)(x + i);
    u32 lo = (u32)f2bf(vv.x) | ((u32)f2bf(vv.y) << 16);
    u32 hi = (u32)f2bf(vv.z) | ((u32)f2bf(vv.w) << 16);
    *(uint2*)(o + i) = make_uint2(lo, hi);
}

// ---------------- GEMM: C[.,N] = A[.,K] @ Bt[N,K]^T ----------------
// BM x BN tile, BK=32, 256 threads, global_load_lds staging, XOR chunk swizzle.
// LDS: row r at element r*32; 64-row staging pass p covers rows [p*64, p*64+64)
// -> base offset p*2048 elements (R4 bug was p*4096: OOB, corrupted tiles).
template <int BM, int BN, bool BF16OUT>
__device__ __forceinline__ void gemm_core(const u16* __restrict__ A, const u16* __restrict__ Bt,
                                          void* __restrict__ Cp, int K, int N, int m0, int n0,
                                          float oscale) {
    constexpr int WROWS = BM / 64;        // 2 (128x128) or 1 (64x128)
    constexpr int WCOLS = 4 / WROWS;      // 2 or 4
    constexpr int BFR = BN / WCOLS / 16;  // 4 or 2
    __shared__ __align__(16) u16 As[BM * 32];
    __shared__ __align__(16) u16 Bs[BN * 32];
    const int tid = threadIdx.x;
    const int lane = tid & 63, wave = tid >> 6;
    const int l16 = lane & 15, q4 = lane >> 4;
    const int wm = (wave / WCOLS) * 64, wn = (wave % WCOLS) * (BFR * 16);

    const f32x4 fz = {0.f, 0.f, 0.f, 0.f};
    f32x4 acc[4][BFR];
#pragma unroll
    for (int i = 0; i < 4; ++i)
#pragma unroll
        for (int j = 0; j < BFR; ++j) acc[i][j] = fz;

    const int rseg = lane >> 2;
    const int ck = ((lane & 3) ^ ((lane >> 3) & 3)) * 8;  // swizzled k-chunk
    const u16* Ag = A + (size_t)(m0 + wave * 16 + rseg) * K + ck;
    const u16* Bg = Bt + (size_t)(n0 + wave * 16 + rseg) * K + ck;

    const int swz = (q4 ^ ((l16 & 7) >> 1)) * 8;

    for (int k0 = 0; k0 < K; k0 += 32) {
        __syncthreads();
#pragma unroll
        for (int p = 0; p < BM / 64; ++p)
            gld16(Ag + (size_t)p * 64 * K + k0, As + p * 2048 + wave * 512);
#pragma unroll
        for (int p = 0; p < BN / 64; ++p)
            gld16(Bg + (size_t)p * 64 * K + k0, Bs + p * 2048 + wave * 512);
        __syncthreads();
        bf16x8 af[4], bfr[BFR];
#pragma unroll
        for (int i = 0; i < 4; ++i)
            af[i] = *(const bf16x8*)&As[(wm + i * 16 + l16) * 32 + swz];
#pragma unroll
        for (int j = 0; j < BFR; ++j)
            bfr[j] = *(const bf16x8*)&Bs[(wn + j * 16 + l16) * 32 + swz];
#pragma unroll
        for (int i = 0; i < 4; ++i)
#pragma unroll
            for (int j = 0; j < BFR; ++j) acc[i][j] = mfma16(af[i], bfr[j], acc[i][j]);
    }

#pragma unroll
    for (int i = 0; i < 4; ++i) {
        const int row = m0 + wm + i * 16 + q4 * 4;
#pragma unroll
        for (int j = 0; j < BFR; ++j) {
            const int col = n0 + wn + j * 16 + l16;
#pragma unroll
            for (int r = 0; r < 4; ++r) {
                const float vr = acc[i][j][r] * oscale;
                if constexpr (BF16OUT)
                    ((u16*)Cp)[(size_t)(row + r) * N + col] = f2bf(vr);
                else
                    ((float*)Cp)[(size_t)(row + r) * N + col] = vr;
            }
        }
    }
}

// z=0: Q = query@wq^T (pre-scaled by 0.125*log2e); z=1: K = key@wk^T;
// z=2: Vt = wv @ value^T -> VtAll[h*64+dv][b*2048+s]
__global__ __launch_bounds__(256) void gemm_qkv(const u16* __restrict__ qb, const u16* __restrict__ kb,
                                                const u16* __restrict__ vb, const u16* __restrict__ wqb,
                                                const u16* __restrict__ wkb, const u16* __restrict__ wvb,
                                                u16* __restrict__ Qp, u16* __restrict__ Kp,
                                                u16* __restrict__ VtAll) {
    const int z = blockIdx.y, x = blockIdx.x;
    const u16 *A, *Bt;
    u16* C;
    int N, m0, n0;
    float sc = 1.0f;
    if (z == 0) {
        A = qb; Bt = wqb; C = Qp; N = 1024; m0 = (x >> 3) * 128; n0 = (x & 7) * 128;
        sc = 0.18033688011112042f;  // (1/sqrt(64)) * log2(e)
    } else if (z == 1) {
        A = kb; Bt = wkb; C = Kp; N = 1024; m0 = (x >> 3) * 128; n0 = (x & 7) * 128;
    } else {
        A = wvb; Bt = vb; C = VtAll; N = 4096; m0 = (x >> 5) * 128; n0 = (x & 31) * 128;
    }
    gemm_core<128, 128, true>(A, Bt, C, 1024, N, m0, n0, sc);
}

__global__ __launch_bounds__(256) void gemm_out(const u16* __restrict__ ctx,
                                                const u16* __restrict__ wob,
                                                float* __restrict__ out) {
    const int x = blockIdx.x;  // 512 blocks: 64 m-tiles x 8 n-tiles
    gemm_core<64, 128, false>(ctx, wob, out, 1024, 1024, (x >> 3) * 64, (x & 7) * 128, 1.0f);
}

// ---------------- Flash attention, S^T/O^T form, k-split partials ----------------
// grid (16, 16, B*NS). Writes fp32 (o,l) partials; combine normalizes.
// Vts 8B sub-chunks XOR-swizzled by (dv>>3)&1 -> conflict-free b64 reads.
__global__ __launch_bounds__(256) void flash_attn(const u16* __restrict__ Qp,
                                                  const u16* __restrict__ Kp,
                                                  const u16* __restrict__ VtAll,
                                                  float* __restrict__ Op0,
                                                  float* __restrict__ Op1,
                                                  float* __restrict__ Lp,
                                                  int NS, int ktLen) {
    constexpr int D = 1024, SS = 2048, LD = 72;
    __shared__ __align__(16) u16 Ks[64 * LD];   // [s_row][dk]
    __shared__ __align__(16) u16 Vts[64 * LD];  // [dv][s], sub-chunk swizzled

    const int tid = threadIdx.x;
    const int lane = tid & 63, wave = tid >> 6;
    const int l16 = lane & 15, q4 = lane >> 4;
    const int h = blockIdx.y;
    const int b = blockIdx.z / NS, half = blockIdx.z - b * NS;
    const int q0 = blockIdx.x * 128 + wave * 32;
    const int kt0 = half * ktLen, ktEnd = kt0 + ktLen;

    bf16x8 qf[2][2];
#pragma unroll
    for (int qs = 0; qs < 2; ++qs) {
        const u16* Qb = Qp + (size_t)(b * SS + q0 + qs * 16 + l16) * D + h * 64;
        qf[qs][0] = *(const bf16x8*)(Qb + q4 * 8);
        qf[qs][1] = *(const bf16x8*)(Qb + 32 + q4 * 8);
    }

    const f32x4 fz = {0.f, 0.f, 0.f, 0.f};
    f32x4 ot[2][4], lacc[2];
    lacc[0] = fz; lacc[1] = fz;
#pragma unroll
    for (int qs = 0; qs < 2; ++qs)
#pragma unroll
        for (int dt = 0; dt < 4; ++dt) ot[qs][dt] = fz;

    s16x4 onesA;
    onesA[0] = onesA[1] = onesA[2] = onesA[3] = (short)0x3F80;  // bf16 1.0

    const int sr = tid >> 3, scol = (tid & 7) * 8;
    const int vswap = wave & 1;            // == (dv>>3)&1 for this wave's staging rows
    const int swV = (l16 >> 3) & 1;        // read-side sub-chunk swizzle key
    const u16* Kg = Kp + (size_t)(b * SS + sr) * D + h * 64 + scol;
    const u16* Vg = VtAll + (size_t)(h * 64 + sr) * 4096 + b * SS + scol;

    uint4 k0v = *(const uint4*)(Kg + (size_t)kt0 * D);
    uint4 k1v = *(const uint4*)(Kg + (size_t)(kt0 + 32) * D);
    uint4 v0v = *(const uint4*)(Vg + kt0);
    uint4 v1v = *(const uint4*)(Vg + (size_t)32 * 4096 + kt0);

    for (int kt = kt0; kt < ktEnd; kt += 64) {
        if (vswap) {  // swap 8B halves: sub-chunk sc lands at position sc^1
            v0v = make_uint4(v0v.z, v0v.w, v0v.x, v0v.y);
            v1v = make_uint4(v1v.z, v1v.w, v1v.x, v1v.y);
        }
        __syncthreads();
        *(uint4*)&Ks[sr * LD + scol] = k0v;
        *(uint4*)&Ks[(sr + 32) * LD + scol] = k1v;
        *(uint4*)&Vts[sr * LD + scol] = v0v;
        *(uint4*)&Vts[(sr + 32) * LD + scol] = v1v;
        __syncthreads();

        const int nk = (kt + 64 < ktEnd) ? kt + 64 : kt0;
        k0v = *(const uint4*)(Kg + (size_t)nk * D);
        k1v = *(const uint4*)(Kg + (size_t)(nk + 32) * D);
        v0v = *(const uint4*)(Vg + nk);
        v1v = *(const uint4*)(Vg + (size_t)32 * 4096 + nk);

        // S^T = K·Q^T (exp2 domain; Q pre-scaled)
        f32x4 st[2][4];
#pragma unroll
        for (int nt = 0; nt < 4; ++nt) {
            const bf16x8 ka = *(const bf16x8*)&Ks[(nt * 16 + l16) * LD + q4 * 8];
            const bf16x8 kbf = *(const bf16x8*)&Ks[(nt * 16 + l16) * LD + 32 + q4 * 8];
#pragma unroll
            for (int qs = 0; qs < 2; ++qs) {
                f32x4 s = mfma16(ka, qf[qs][0], fz);
                st[qs][nt] = mfma16(kbf, qf[qs][1], s);
            }
        }
        // P^T = exp2(S^T), in-register (K=16 B-frag layout)
        s16x4 p[2][4];
#pragma unroll
        for (int qs = 0; qs < 2; ++qs)
#pragma unroll
            for (int nt = 0; nt < 4; ++nt) {
                s16x4 pk;
#pragma unroll
                for (int r = 0; r < 4; ++r)
                    pk[r] = (short)f2bf(__builtin_amdgcn_exp2f(st[qs][nt][r]));
                p[qs][nt] = pk;
            }
        // O^T += V^T·P^T ; l via ones-MFMA (all regs = l[q=l16])
#pragma unroll
        for (int nt = 0; nt < 4; ++nt) {
#pragma unroll
            for (int dt = 0; dt < 4; ++dt) {
                const s16x4 va = *(const s16x4*)&Vts[(dt * 16 + l16) * LD + ((nt * 4 + q4) ^ swV) * 4];
                ot[0][dt] = mfma16k16(va, p[0][nt], ot[0][dt]);
                ot[1][dt] = mfma16k16(va, p[1][nt], ot[1][dt]);
            }
            lacc[0] = mfma16k16(onesA, p[0][nt], lacc[0]);
            lacc[1] = mfma16k16(onesA, p[1][nt], lacc[1]);
        }
    }

    float* Op = half ? Op1 : Op0;
#pragma unroll
    for (int qs = 0; qs < 2; ++qs) {
        const int q = q0 + qs * 16 + l16;
        float* orow = Op + (size_t)(b * SS + q) * 1024 + h * 64;
#pragma unroll
        for (int dt = 0; dt < 4; ++dt)
            *(f32x4*)(orow + dt * 16 + q4 * 4) = ot[qs][dt];
        if (lane < 16)  // q4==0 lanes hold l[q0+qs*16+l16]
            Lp[((half * 2 + b) * 16 + h) * 2048 + q] = lacc[qs][0];
    }
}

// ---------------- combine: ctx = bf16( sum(o)/sum(l) ) ----------------
__global__ __launch_bounds__(256) void combine(const float* __restrict__ Op0,
                                               const float* __restrict__ Op1,
                                               const float* __restrict__ Lp,
                                               u16* __restrict__ ctx, int NS) {
    const int t = blockIdx.x * 256 + threadIdx.x;  // 1,048,576 threads
    const int e = t * 4;
    const int d = e & 1023, bq = e >> 10;
    const int h = d >> 6, b = bq >> 11, q = bq & 2047;
    f32x4 o = *(const f32x4*)(Op0 + (size_t)bq * 1024 + d);
    float l = Lp[(b * 16 + h) * 2048 + q];
    if (NS == 2) {
        o += *(const f32x4*)(Op1 + (size_t)bq * 1024 + d);
        l += Lp[((2 + b) * 16 + h) * 2048 + q];
    }
    const float inv = 1.f / l;
    s16x4 w;
#pragma unroll
    for (int r = 0; r < 4; ++r) w[r] = (short)f2bf(o[r] * inv);
    *(s16x4*)(ctx + (size_t)bq * 1024 + d) = w;
}

extern "C" void kernel_launch(void* const* d_in, const int* in_sizes, int n_in,
                              void* d_out, int out_size, void* d_ws, size_t ws_size,
                              hipStream_t stream) {
    const float* query = (const float*)d_in[0];
    const float* key   = (const float*)d_in[1];
    const float* value = (const float*)d_in[2];
    const float* w_q   = (const float*)d_in[3];
    const float* w_k   = (const float*)d_in[4];
    const float* w_v   = (const float*)d_in[5];
    const float* w_o   = (const float*)d_in[6];
    float* out = (float*)d_out;

    const size_t MEG = 1024 * 1024;
    if (ws_size < 64 * MEG) return;  // baseline layout needs 64 MiB
    u16* ws = (u16*)d_ws;
    u16* qb    = ws;             // dead after gemm_qkv -> reused as Op0
    u16* kb    = ws + 4 * MEG;
    u16* vb    = ws + 8 * MEG;
    u16* wqb   = ws + 12 * MEG;  // dead after gemm_qkv -> reused as Lp
    u16* wkb   = ws + 13 * MEG;
    u16* wvb   = ws + 14 * MEG;
    u16* wob   = ws + 15 * MEG;  // live until gemm_out
    u16* Qp    = ws + 16 * MEG;
    u16* Kp    = ws + 20 * MEG;
    u16* VtAll = ws + 24 * MEG;
    u16* ctx   = ws + 28 * MEG;  // ends at 32 MEG u16 = 64 MiB

    float* Op0 = (float*)ws;              // 16 MiB (qb+kb region)
    float* Lp  = (float*)(ws + 12 * MEG); // <=512 KiB (wqb region)
    float* Op1 = (float*)(ws + 32 * MEG); // bytes [64 MiB, 80 MiB) if available

    const int NS = (ws_size >= 80 * MEG) ? 2 : 1;  // k-split occupancy x2 when ws allows
    const int ktLen = 2048 / NS;

    cvt_all<<<dim3(4096, 7), 256, 0, stream>>>(query, key, value, w_q, w_k, w_v, w_o,
                                               qb, kb, vb, wqb, wkb, wvb, wob);
    gemm_qkv<<<dim3(256, 3), 256, 0, stream>>>(qb, kb, vb, wqb, wkb, wvb, Qp, Kp, VtAll);
    flash_attn<<<dim3(16, 16, 2 * NS), 256, 0, stream>>>(Qp, Kp, VtAll, Op0, Op1, Lp, NS, ktLen);
    combine<<<dim3(4096), 256, 0, stream>>>(Op0, Op1, Lp, ctx, NS);
    gemm_out<<<dim3(512), 256, 0, stream>>>(ctx, wob, out);
}

// Round 6
// 217.309 us; speedup vs baseline: 1.0554x; 1.0554x over previous
//
#include <hip/hip_runtime.h>

typedef unsigned short u16;
typedef unsigned int u32;
typedef __bf16 bf16x8 __attribute__((ext_vector_type(8)));
typedef float f32x4 __attribute__((ext_vector_type(4)));
typedef short s16x4 __attribute__((ext_vector_type(4)));

#define AS1 __attribute__((address_space(1)))
#define AS3 __attribute__((address_space(3)))

__device__ __forceinline__ f32x4 mfma16(bf16x8 a, bf16x8 b, f32x4 c) {
    return __builtin_amdgcn_mfma_f32_16x16x32_bf16(a, b, c, 0, 0, 0);
}
// K=16 shape: B-operand layout == C/D layout (transpose-free PV)
__device__ __forceinline__ f32x4 mfma16k16(s16x4 a, s16x4 b, f32x4 c) {
    return __builtin_amdgcn_mfma_f32_16x16x16bf16_1k(a, b, c, 0, 0, 0);
}

__device__ __forceinline__ u16 f2bf(float f) {
    return __builtin_bit_cast(u16, (__bf16)f);
}

__device__ __forceinline__ void gld16(const u16* g, u16* l) {
    __builtin_amdgcn_global_load_lds((AS1 void*)g, (AS3 void*)l, 16, 0, 0);
}

// ---------------- fused fp32 -> bf16 conversion ----------------
__global__ __launch_bounds__(256) void cvt_all(const float* __restrict__ q, const float* __restrict__ k,
                                               const float* __restrict__ v, const float* __restrict__ wq,
                                               const float* __restrict__ wk, const float* __restrict__ wv,
                                               const float* __restrict__ wo, u16* __restrict__ qo,
                                               u16* __restrict__ ko, u16* __restrict__ vo,
                                               u16* __restrict__ wqo, u16* __restrict__ wko,
                                               u16* __restrict__ wvo, u16* __restrict__ woo) {
    const int y = blockIdx.y;
    const float* x; u16* o; int n;
    switch (y) {
        case 0: x = q; o = qo; n = 4 << 20; break;
        case 1: x = k; o = ko; n = 4 << 20; break;
        case 2: x = v; o = vo; n = 4 << 20; break;
        case 3: x = wq; o = wqo; n = 1 << 20; break;
        case 4: x = wk; o = wko; n = 1 << 20; break;
        case 5: x = wv; o = wvo; n = 1 << 20; break;
        default: x = wo; o = woo; n = 1 << 20; break;
    }
    int i = (blockIdx.x * 256 + threadIdx.x) * 4;
    if (i >= n) return;
    float4 vv = *(const float4*)(x + i);
    u32 lo = (u32)f2bf(vv.x) | ((u32)f2bf(vv.y) << 16);
    u32 hi = (u32)f2bf(vv.z) | ((u32)f2bf(vv.w) << 16);
    *(uint2*)(o + i) = make_uint2(lo, hi);
}

// ---------------- GEMM: C[.,N] = A[.,K] @ Bt[N,K]^T ----------------
// BM x BN tile, BK=32, 256 threads, global_load_lds staging, XOR chunk swizzle.
// LDS: row r at element r*32; 64-row staging pass p covers rows [p*64, p*64+64)
// -> base offset p*2048 elements.
template <int BM, int BN, bool BF16OUT>
__device__ __forceinline__ void gemm_core(const u16* __restrict__ A, const u16* __restrict__ Bt,
                                          void* __restrict__ Cp, int K, int N, int m0, int n0,
                                          float oscale) {
    constexpr int WROWS = BM / 64;        // 2 (128x128) or 1 (64x128)
    constexpr int WCOLS = 4 / WROWS;      // 2 or 4
    constexpr int BFR = BN / WCOLS / 16;  // 4 or 2
    __shared__ __align__(16) u16 As[BM * 32];
    __shared__ __align__(16) u16 Bs[BN * 32];
    const int tid = threadIdx.x;
    const int lane = tid & 63, wave = tid >> 6;
    const int l16 = lane & 15, q4 = lane >> 4;
    const int wm = (wave / WCOLS) * 64, wn = (wave % WCOLS) * (BFR * 16);

    const f32x4 fz = {0.f, 0.f, 0.f, 0.f};
    f32x4 acc[4][BFR];
#pragma unroll
    for (int i = 0; i < 4; ++i)
#pragma unroll
        for (int j = 0; j < BFR; ++j) acc[i][j] = fz;

    const int rseg = lane >> 2;
    const int ck = ((lane & 3) ^ ((lane >> 3) & 3)) * 8;  // swizzled k-chunk
    const u16* Ag = A + (size_t)(m0 + wave * 16 + rseg) * K + ck;
    const u16* Bg = Bt + (size_t)(n0 + wave * 16 + rseg) * K + ck;

    const int swz = (q4 ^ ((l16 & 7) >> 1)) * 8;

    for (int k0 = 0; k0 < K; k0 += 32) {
        __syncthreads();
#pragma unroll
        for (int p = 0; p < BM / 64; ++p)
            gld16(Ag + (size_t)p * 64 * K + k0, As + p * 2048 + wave * 512);
#pragma unroll
        for (int p = 0; p < BN / 64; ++p)
            gld16(Bg + (size_t)p * 64 * K + k0, Bs + p * 2048 + wave * 512);
        __syncthreads();
        bf16x8 af[4], bfr[BFR];
#pragma unroll
        for (int i = 0; i < 4; ++i)
            af[i] = *(const bf16x8*)&As[(wm + i * 16 + l16) * 32 + swz];
#pragma unroll
        for (int j = 0; j < BFR; ++j)
            bfr[j] = *(const bf16x8*)&Bs[(wn + j * 16 + l16) * 32 + swz];
#pragma unroll
        for (int i = 0; i < 4; ++i)
#pragma unroll
            for (int j = 0; j < BFR; ++j) acc[i][j] = mfma16(af[i], bfr[j], acc[i][j]);
    }

#pragma unroll
    for (int i = 0; i < 4; ++i) {
        const int row = m0 + wm + i * 16 + q4 * 4;
#pragma unroll
        for (int j = 0; j < BFR; ++j) {
            const int col = n0 + wn + j * 16 + l16;
#pragma unroll
            for (int r = 0; r < 4; ++r) {
                const float vr = acc[i][j][r] * oscale;
                if constexpr (BF16OUT)
                    ((u16*)Cp)[(size_t)(row + r) * N + col] = f2bf(vr);
                else
                    ((float*)Cp)[(size_t)(row + r) * N + col] = vr;
            }
        }
    }
}

// z=0: Q = query@wq^T (pre-scaled by 0.125*log2e); z=1: K = key@wk^T;
// z=2: Vt = wv @ value^T -> VtAll[h*64+dv][b*2048+s]
__global__ __launch_bounds__(256) void gemm_qkv(const u16* __restrict__ qb, const u16* __restrict__ kb,
                                                const u16* __restrict__ vb, const u16* __restrict__ wqb,
                                                const u16* __restrict__ wkb, const u16* __restrict__ wvb,
                                                u16* __restrict__ Qp, u16* __restrict__ Kp,
                                                u16* __restrict__ VtAll) {
    const int z = blockIdx.y, x = blockIdx.x;
    const u16 *A, *Bt;
    u16* C;
    int N, m0, n0;
    float sc = 1.0f;
    if (z == 0) {
        A = qb; Bt = wqb; C = Qp; N = 1024; m0 = (x >> 3) * 128; n0 = (x & 7) * 128;
        sc = 0.18033688011112042f;  // (1/sqrt(64)) * log2(e)
    } else if (z == 1) {
        A = kb; Bt = wkb; C = Kp; N = 1024; m0 = (x >> 3) * 128; n0 = (x & 7) * 128;
    } else {
        A = wvb; Bt = vb; C = VtAll; N = 4096; m0 = (x >> 5) * 128; n0 = (x & 31) * 128;
    }
    gemm_core<128, 128, true>(A, Bt, C, 1024, N, m0, n0, sc);
}

__global__ __launch_bounds__(256) void gemm_out(const u16* __restrict__ ctx,
                                                const u16* __restrict__ wob,
                                                float* __restrict__ out) {
    const int x = blockIdx.x;  // 512 blocks: 64 m-tiles x 8 n-tiles
    gemm_core<64, 128, false>(ctx, wob, out, 1024, 1024, (x >> 3) * 64, (x & 7) * 128, 1.0f);
}

// ---------------- Flash attention: S^T/O^T form, LDS double-buffer, 1 barrier/tile ----
// iter t: write buf[t&1] (regs prefetched at t-1) -> issue loads t+1 -> barrier -> compute.
// Safety: overwrite of buf[t&1] next happens in iter t+2, after barrier t+1, which a wave
// reaches only after finishing compute t. One __syncthreads per 64-s tile.
// grid (16, 16, 2), 256 threads; wave owns 32 q-rows; writes bf16 ctx directly.
__global__ __launch_bounds__(256) void flash_attn(const u16* __restrict__ Qp,
                                                  const u16* __restrict__ Kp,
                                                  const u16* __restrict__ VtAll,
                                                  u16* __restrict__ Ctx) {
    constexpr int D = 1024, SS = 2048, LD = 72;
    __shared__ __align__(16) u16 Ks[2][64 * LD];   // [buf][s_row][dk]
    __shared__ __align__(16) u16 Vts[2][64 * LD];  // [buf][dv][s], 8B sub-chunk swizzled

    const int tid = threadIdx.x;
    const int lane = tid & 63, wave = tid >> 6;
    const int l16 = lane & 15, q4 = lane >> 4;
    const int h = blockIdx.y, b = blockIdx.z;
    const int q0 = blockIdx.x * 128 + wave * 32;

    bf16x8 qf[2][2];
#pragma unroll
    for (int qs = 0; qs < 2; ++qs) {
        const u16* Qb = Qp + (size_t)(b * SS + q0 + qs * 16 + l16) * D + h * 64;
        qf[qs][0] = *(const bf16x8*)(Qb + q4 * 8);
        qf[qs][1] = *(const bf16x8*)(Qb + 32 + q4 * 8);
    }

    const f32x4 fz = {0.f, 0.f, 0.f, 0.f};
    f32x4 ot[2][4], lacc[2];
    lacc[0] = fz; lacc[1] = fz;
#pragma unroll
    for (int qs = 0; qs < 2; ++qs)
#pragma unroll
        for (int dt = 0; dt < 4; ++dt) ot[qs][dt] = fz;

    s16x4 onesA;
    onesA[0] = onesA[1] = onesA[2] = onesA[3] = (short)0x3F80;  // bf16 1.0

    const int sr = tid >> 3, scol = (tid & 7) * 8;
    const int vswap = wave & 1;      // == (dv>>3)&1 for this wave's staging rows
    const int swV = (l16 >> 3) & 1;  // read-side sub-chunk swizzle key
    const u16* Kg = Kp + (size_t)(b * SS + sr) * D + h * 64 + scol;
    const u16* Vg = VtAll + (size_t)(h * 64 + sr) * 4096 + b * SS + scol;

    uint4 k0v = *(const uint4*)(Kg);
    uint4 k1v = *(const uint4*)(Kg + (size_t)32 * D);
    uint4 v0v = *(const uint4*)(Vg);
    uint4 v1v = *(const uint4*)(Vg + (size_t)32 * 4096);

    for (int kt = 0; kt < SS; kt += 64) {
        const int buf = (kt >> 6) & 1;
        uint4 w0 = v0v, w1 = v1v;
        if (vswap) {  // swap 8B halves: sub-chunk sc lands at position sc^1
            w0 = make_uint4(v0v.z, v0v.w, v0v.x, v0v.y);
            w1 = make_uint4(v1v.z, v1v.w, v1v.x, v1v.y);
        }
        *(uint4*)&Ks[buf][sr * LD + scol] = k0v;
        *(uint4*)&Ks[buf][(sr + 32) * LD + scol] = k1v;
        *(uint4*)&Vts[buf][sr * LD + scol] = w0;
        *(uint4*)&Vts[buf][(sr + 32) * LD + scol] = w1;

        const int nk = (kt + 64 < SS) ? kt + 64 : 0;  // wrap: harmless L2 re-read
        k0v = *(const uint4*)(Kg + (size_t)nk * D);
        k1v = *(const uint4*)(Kg + (size_t)(nk + 32) * D);
        v0v = *(const uint4*)(Vg + nk);
        v1v = *(const uint4*)(Vg + (size_t)32 * 4096 + nk);

        __syncthreads();

        // S^T = K·Q^T (exp2 domain; Q pre-scaled by 0.125*log2e)
        f32x4 st[2][4];
#pragma unroll
        for (int nt = 0; nt < 4; ++nt) {
            const bf16x8 ka = *(const bf16x8*)&Ks[buf][(nt * 16 + l16) * LD + q4 * 8];
            const bf16x8 kbf = *(const bf16x8*)&Ks[buf][(nt * 16 + l16) * LD + 32 + q4 * 8];
#pragma unroll
            for (int qs = 0; qs < 2; ++qs) {
                f32x4 s = mfma16(ka, qf[qs][0], fz);
                st[qs][nt] = mfma16(kbf, qf[qs][1], s);
            }
        }
        // P^T = exp2(S^T), in-register (K=16 B-frag layout)
        s16x4 p[2][4];
#pragma unroll
        for (int qs = 0; qs < 2; ++qs)
#pragma unroll
            for (int nt = 0; nt < 4; ++nt) {
                s16x4 pk;
#pragma unroll
                for (int r = 0; r < 4; ++r)
                    pk[r] = (short)f2bf(__builtin_amdgcn_exp2f(st[qs][nt][r]));
                p[qs][nt] = pk;
            }
        // O^T += V^T·P^T ; l via ones-MFMA (every reg = l[q=l16])
#pragma unroll
        for (int nt = 0; nt < 4; ++nt) {
#pragma unroll
            for (int dt = 0; dt < 4; ++dt) {
                const s16x4 va =
                    *(const s16x4*)&Vts[buf][(dt * 16 + l16) * LD + ((nt * 4 + q4) ^ swV) * 4];
                ot[0][dt] = mfma16k16(va, p[0][nt], ot[0][dt]);
                ot[1][dt] = mfma16k16(va, p[1][nt], ot[1][dt]);
            }
            lacc[0] = mfma16k16(onesA, p[0][nt], lacc[0]);
            lacc[1] = mfma16k16(onesA, p[1][nt], lacc[1]);
        }
    }

    // normalize + direct bf16 ctx write (lacc broadcast: all regs hold l[q=l16])
#pragma unroll
    for (int qs = 0; qs < 2; ++qs) {
        const float inv = 1.f / lacc[qs][0];
        u16* Cb = Ctx + (size_t)(b * SS + q0 + qs * 16 + l16) * D + h * 64 + q4 * 4;
#pragma unroll
        for (int dt = 0; dt < 4; ++dt) {
            s16x4 w;
#pragma unroll
            for (int r = 0; r < 4; ++r) w[r] = (short)f2bf(ot[qs][dt][r] * inv);
            *(s16x4*)(Cb + dt * 16) = w;  // O[q][dv], dv = dt*16 + q4*4 + r
        }
    }
}

extern "C" void kernel_launch(void* const* d_in, const int* in_sizes, int n_in,
                              void* d_out, int out_size, void* d_ws, size_t ws_size,
                              hipStream_t stream) {
    const float* query = (const float*)d_in[0];
    const float* key   = (const float*)d_in[1];
    const float* value = (const float*)d_in[2];
    const float* w_q   = (const float*)d_in[3];
    const float* w_k   = (const float*)d_in[4];
    const float* w_v   = (const float*)d_in[5];
    const float* w_o   = (const float*)d_in[6];
    float* out = (float*)d_out;

    const size_t MEG = 1024 * 1024;
    if (ws_size < 64 * MEG) return;  // layout needs 64 MiB
    u16* ws = (u16*)d_ws;
    u16* qb    = ws;
    u16* kb    = ws + 4 * MEG;
    u16* vb    = ws + 8 * MEG;
    u16* wqb   = ws + 12 * MEG;
    u16* wkb   = ws + 13 * MEG;
    u16* wvb   = ws + 14 * MEG;
    u16* wob   = ws + 15 * MEG;  // live until gemm_out
    u16* Qp    = ws + 16 * MEG;
    u16* Kp    = ws + 20 * MEG;
    u16* VtAll = ws + 24 * MEG;
    u16* ctx   = ws + 28 * MEG;  // ends at 32 MEG u16 = 64 MiB

    cvt_all<<<dim3(4096, 7), 256, 0, stream>>>(query, key, value, w_q, w_k, w_v, w_o,
                                               qb, kb, vb, wqb, wkb, wvb, wob);
    gemm_qkv<<<dim3(256, 3), 256, 0, stream>>>(qb, kb, vb, wqb, wkb, wvb, Qp, Kp, VtAll);
    flash_attn<<<dim3(16, 16, 2), 256, 0, stream>>>(Qp, Kp, VtAll, ctx);
    gemm_out<<<dim3(512), 256, 0, stream>>>(ctx, wob, out);
}